// Round 9
// baseline (162.411 us; speedup 1.0000x reference)
//
#include <hip/hip_runtime.h>

constexpr int Bn = 2;
constexpr int Sn = 4096;
constexpr int Hh = 16;
constexpr int Dn = 64;
constexpr int HD = 1024;   // Hh * Dn
constexpr int NB = 64;     // Sn / 64
constexpr int KS = 7;      // ceil(0.1 * 64)

typedef _Float16 f16x8 __attribute__((ext_vector_type(8)));
typedef _Float16 f16x4 __attribute__((ext_vector_type(4)));
typedef _Float16 f16x2 __attribute__((ext_vector_type(2)));
typedef __fp16   hf2   __attribute__((ext_vector_type(2)));
typedef float    f32x4 __attribute__((ext_vector_type(4)));

static __device__ __forceinline__ f16x8 cvt8(float4 a, float4 b) {
    f16x8 r;
    r[0] = (_Float16)a.x; r[1] = (_Float16)a.y;
    r[2] = (_Float16)a.z; r[3] = (_Float16)a.w;
    r[4] = (_Float16)b.x; r[5] = (_Float16)b.y;
    r[6] = (_Float16)b.z; r[7] = (_Float16)b.w;
    return r;
}

static __device__ __forceinline__ f16x4 pk4(float a, float b, float c, float d) {
    hf2 lo = __builtin_amdgcn_cvt_pkrtz(a, b);
    hf2 hi = __builtin_amdgcn_cvt_pkrtz(c, d);
    f16x2 l2 = __builtin_bit_cast(f16x2, lo);
    f16x2 h2 = __builtin_bit_cast(f16x2, hi);
    f16x4 r;
    r[0] = l2[0]; r[1] = l2[1]; r[2] = h2[0]; r[3] = h2[1];
    return r;
}

// ============ kernel 0 (fast path): fused pool + f16 convert/transpose ============
// Kh[bid][key][d]: f16, 16B chunk ch of row stored at slot ch^(key&7)  (LDS-bank
// swizzle baked into GLOBAL layout so attn's global_load_lds copy is linear).
// Vt[bid][d][key]: f16 transposed; 4-elem chunk (key>>2) stored at slot (key>>2)^(d&15).
__global__ __launch_bounds__(256) void sla_prep(const float* __restrict__ Q,
                                                const float* __restrict__ K,
                                                const float* __restrict__ V,
                                                float* __restrict__ qpool,
                                                float* __restrict__ kpool,
                                                _Float16* __restrict__ Kh,
                                                _Float16* __restrict__ Vt) {
    __shared__ float Tl[64][68];          // stride 68: 16B-aligned rows, bank-rotated

    int bid = blockIdx.x;                 // (b*Hh + h)*NB + nb
    int b   = bid / (Hh * NB);
    int rem = bid % (Hh * NB);
    int h   = rem / NB;
    int nb  = rem % NB;

    int t  = threadIdx.x;
    int r  = t >> 2;                      // row / key 0..63
    int q4 = t & 3;
    int dq = q4 << 4;

    const size_t rowbase = ((size_t)b * Sn + (size_t)nb * 64) * HD + h * Dn;
    const float* qp = Q + rowbase + (size_t)r * HD + dq;
    const float* kp = K + rowbase + (size_t)r * HD + dq;
    const float* vp = V + rowbase + (size_t)r * HD + dq;

    float4 qx[4], kx[4], vx[4];
    #pragma unroll
    for (int i = 0; i < 4; ++i) qx[i] = *(const float4*)(qp + i * 4);
    #pragma unroll
    for (int i = 0; i < 4; ++i) kx[i] = *(const float4*)(kp + i * 4);
    #pragma unroll
    for (int i = 0; i < 4; ++i) vx[i] = *(const float4*)(vp + i * 4);

    // ---- Q: stage + fp64 column means ----
    #pragma unroll
    for (int i = 0; i < 4; ++i) *(float4*)&Tl[r][dq + i * 4] = qx[i];
    __syncthreads();
    if (t < 64) {
        double s = 0.0;
        #pragma unroll 8
        for (int rr = 0; rr < 64; ++rr) s += (double)Tl[rr][t];
        qpool[(size_t)bid * 64 + t] = (float)(s * (1.0 / 64.0));
    }
    __syncthreads();

    // ---- K: write swizzled f16 + stage + fp64 column means ----
    {
        _Float16* khrow = Kh + ((size_t)bid * 64 + r) * 64;
        int s0 = ((q4 << 1) + 0) ^ (r & 7);
        int s1 = ((q4 << 1) + 1) ^ (r & 7);
        *(f16x8*)(khrow + (s0 << 3)) = cvt8(kx[0], kx[1]);   // d dq..dq+7
        *(f16x8*)(khrow + (s1 << 3)) = cvt8(kx[2], kx[3]);   // d dq+8..dq+15
    }
    #pragma unroll
    for (int i = 0; i < 4; ++i) *(float4*)&Tl[r][dq + i * 4] = kx[i];
    __syncthreads();
    if (t < 64) {
        double s = 0.0;
        #pragma unroll 8
        for (int rr = 0; rr < 64; ++rr) s += (double)Tl[rr][t];
        kpool[(size_t)bid * 64 + t] = (float)(s * (1.0 / 64.0));
    }
    __syncthreads();

    // ---- V: stage, then write transposed + swizzled f16 ----
    #pragma unroll
    for (int i = 0; i < 4; ++i) *(float4*)&Tl[r][dq + i * 4] = vx[i];
    __syncthreads();
    {
        int d  = r;                       // output row = d
        _Float16* vtrow = Vt + ((size_t)bid * 64 + d) * 64;
        #pragma unroll
        for (int si = 0; si < 4; ++si) {
            int s  = (q4 << 2) + si;      // slot 0..15
            int ch = s ^ (d & 15);        // key chunk stored at this slot
            f16x4 v4;
            v4[0] = (_Float16)Tl[(ch << 2) + 0][d];
            v4[1] = (_Float16)Tl[(ch << 2) + 1][d];
            v4[2] = (_Float16)Tl[(ch << 2) + 2][d];
            v4[3] = (_Float16)Tl[(ch << 2) + 3][d];
            *(f16x4*)(vtrow + (s << 2)) = v4;
        }
    }
}

// ---------------- kernel 1 (fallback path): per-block mean pooling ----------------
__global__ __launch_bounds__(64) void sla_pool(const float* __restrict__ Q,
                                               const float* __restrict__ K,
                                               float* __restrict__ qpool,
                                               float* __restrict__ kpool) {
    int bid  = blockIdx.x;
    int b    = bid / (Hh * NB);
    int rem  = bid % (Hh * NB);
    int h    = rem / NB;
    int nb   = rem % NB;
    int tid  = threadIdx.x;
    int quad = tid >> 4;
    int dq   = (tid & 15) << 2;

    const float* qb = Q + ((size_t)b * Sn + (size_t)nb * 64) * HD + h * Dn + dq;
    const float* kb = K + ((size_t)b * Sn + (size_t)nb * 64) * HD + h * Dn + dq;

    double sq[4] = {0, 0, 0, 0}, sk[4] = {0, 0, 0, 0};
    #pragma unroll
    for (int i = 0; i < 16; ++i) {
        size_t off = (size_t)(quad + i * 4) * HD;
        float4 x = *(const float4*)(qb + off);
        float4 y = *(const float4*)(kb + off);
        sq[0] += x.x; sq[1] += x.y; sq[2] += x.z; sq[3] += x.w;
        sk[0] += y.x; sk[1] += y.y; sk[2] += y.z; sk[3] += y.w;
    }
    #pragma unroll
    for (int j = 0; j < 4; ++j) {
        sq[j] += __shfl_xor(sq[j], 16); sq[j] += __shfl_xor(sq[j], 32);
        sk[j] += __shfl_xor(sk[j], 16); sk[j] += __shfl_xor(sk[j], 32);
    }
    if (quad == 0) {
        float4 oq, ok;
        oq.x = (float)(sq[0] * (1.0 / 64.0)); oq.y = (float)(sq[1] * (1.0 / 64.0));
        oq.z = (float)(sq[2] * (1.0 / 64.0)); oq.w = (float)(sq[3] * (1.0 / 64.0));
        ok.x = (float)(sk[0] * (1.0 / 64.0)); ok.y = (float)(sk[1] * (1.0 / 64.0));
        ok.z = (float)(sk[2] * (1.0 / 64.0)); ok.w = (float)(sk[3] * (1.0 / 64.0));
        *(float4*)(qpool + (size_t)bid * 64 + dq) = oq;
        *(float4*)(kpool + (size_t)bid * 64 + dq) = ok;
    }
}

// -------- kernel 2: block scores (fp64) + top-7 selection (lax.top_k ties: lower idx) --------
__global__ __launch_bounds__(64) void sla_topk(const float* __restrict__ qpool,
                                               const float* __restrict__ kpool,
                                               int* __restrict__ topk) {
    int bid = blockIdx.x;
    int bh  = bid / NB;
    int j   = threadIdx.x;

    const float* qp = qpool + (size_t)bid * 64;
    const float* kp = kpool + ((size_t)bh * NB + j) * 64;
    double s = 0.0;
    #pragma unroll 8
    for (int d = 0; d < 64; ++d) s += (double)qp[d] * (double)kp[d];

    double v  = s;
    int   idx = j;
    #pragma unroll
    for (int it = 0; it < KS; ++it) {
        double bv = v; int bi = idx;
        #pragma unroll
        for (int off = 1; off < 64; off <<= 1) {
            double ov = __shfl_xor(bv, off);
            int    oi = __shfl_xor(bi, off);
            if (ov > bv || (ov == bv && oi < bi)) { bv = ov; bi = oi; }
        }
        if (j == 0) topk[(size_t)bid * KS + it] = bi;
        if (idx == bi) v = -1e300;
    }
}

// ======== kernel 3 (fast path): 1-wave flash attention over pre-converted f16 ========
// Gathers are linear 8KB global_load_lds copies of pre-swizzled blocks; counted
// vmcnt(8) pipeline; QK reads conflict-free b128; PV reads conflict-free b64;
// P stays in registers as 16x16x16 B-fragments; no max-subtraction.
__global__ __launch_bounds__(64) void sla_attn16(const float* __restrict__ Q,
                                                 const _Float16* __restrict__ Kh,
                                                 const _Float16* __restrict__ Vt,
                                                 const int* __restrict__ topk,
                                                 float* __restrict__ O) {
    __shared__ _Float16 Kl[4096];         // 8KB [key][slot] (pre-swizzled)
    __shared__ _Float16 Vl[4096];         // 8KB [d][slot]   (pre-swizzled)

    int raw = blockIdx.x;
    int bid = (raw & 7) * 256 + (raw >> 3);   // XCD-chunked swizzle (2048 = 8*256)

    int b   = bid / (Hh * NB);
    int rem = bid % (Hh * NB);
    int h   = rem / NB;
    int nb  = rem % NB;

    int lane = threadIdx.x & 63;
    int c    = lane & 15;
    int g    = lane >> 4;

    // hoist 7 block indices to SGPRs (static indexing only; loop fully unrolled)
    int jidx[KS];
    {
        const int* tkp = topk + (size_t)bid * KS;
        #pragma unroll
        for (int i = 0; i < KS; ++i)
            jidx[i] = __builtin_amdgcn_readfirstlane(tkp[i]);
    }

    const size_t bhbase = (size_t)(bid - nb) * 4096;   // (bh*NB)*4096
    const float* qbase  = Q + ((size_t)b * Sn + (size_t)nb * 64) * HD + h * Dn;

    // linear 8KB copy: 8 chunks x (64 lanes x 16B = 1024B = 512 f16)
    auto ISSUE8 = [&](const _Float16* blkbase, _Float16* ldsbase) {
        #pragma unroll
        for (int ch = 0; ch < 8; ++ch) {
            const _Float16* src = blkbase + ch * 512 + lane * 8;
            __builtin_amdgcn_global_load_lds(
                (const __attribute__((address_space(1))) void*)src,
                (__attribute__((address_space(3))) void*)(ldsbase + ch * 512),
                16, 0, 0);
        }
    };

    // ---- Q loads first (oldest vmcnt slots), then block-0 staging ----
    float4 qraw[4][2][2];
    #pragma unroll
    for (int f = 0; f < 4; ++f) {
        const float* qrow = qbase + (size_t)(f * 16 + c) * HD;
        #pragma unroll
        for (int s2 = 0; s2 < 2; ++s2) {
            qraw[f][s2][0] = *(const float4*)(qrow + s2 * 32 + g * 8);
            qraw[f][s2][1] = *(const float4*)(qrow + s2 * 32 + g * 8 + 4);
        }
    }
    ISSUE8(Kh + bhbase + (size_t)jidx[0] * 4096, Kl);
    ISSUE8(Vt + bhbase + (size_t)jidx[0] * 4096, Vl);

    // ---- Q fragments; scale = 0.125 * log2(e) (softmax in log2 domain) ----
    const float QS = 0.18033688f;
    f16x8 qf[4][2];
    #pragma unroll
    for (int f = 0; f < 4; ++f) {
        #pragma unroll
        for (int s2 = 0; s2 < 2; ++s2) {
            float4 a0 = qraw[f][s2][0], a1 = qraw[f][s2][1];
            f16x8 q;
            q[0] = (_Float16)(a0.x * QS); q[1] = (_Float16)(a0.y * QS);
            q[2] = (_Float16)(a0.z * QS); q[3] = (_Float16)(a0.w * QS);
            q[4] = (_Float16)(a1.x * QS); q[5] = (_Float16)(a1.y * QS);
            q[6] = (_Float16)(a1.z * QS); q[7] = (_Float16)(a1.w * QS);
            qf[f][s2] = q;
        }
    }

    f32x4 oacc[4][4];
    #pragma unroll
    for (int f = 0; f < 4; ++f)
        #pragma unroll
        for (int tt = 0; tt < 4; ++tt) oacc[f][tt] = f32x4{0.f, 0.f, 0.f, 0.f};
    float rl[4] = {0.f, 0.f, 0.f, 0.f};

    int ks0 = (g ^ (c & 7)) << 3;         // QK slot offset (f16) within 64-elem row

    #pragma unroll
    for (int kb = 0; kb < KS; ++kb) {
        // wait: K[kb] staged (V[kb] still in flight)
        asm volatile("s_waitcnt vmcnt(8)" ::: "memory");

        // ---- QK: S^T[key=16t+4g+i][q=16f+c] ----
        f32x4 sacc[4][4];
        #pragma unroll
        for (int f = 0; f < 4; ++f)
            #pragma unroll
            for (int t = 0; t < 4; ++t) sacc[f][t] = f32x4{0.f, 0.f, 0.f, 0.f};
        __builtin_amdgcn_s_setprio(1);
        #pragma unroll
        for (int t = 0; t < 4; ++t) {
            int rb = (t * 16 + c) * 64;
            f16x8 a0 = *(const f16x8*)&Kl[rb + ks0];          // d 8g..8g+7
            f16x8 a1 = *(const f16x8*)&Kl[rb + (ks0 ^ 32)];   // d 32+8g..+7
            #pragma unroll
            for (int f = 0; f < 4; ++f) {
                sacc[f][t] = __builtin_amdgcn_mfma_f32_16x16x32_f16(a0, qf[f][0], sacc[f][t], 0, 0, 0);
                sacc[f][t] = __builtin_amdgcn_mfma_f32_16x16x32_f16(a1, qf[f][1], sacc[f][t], 0, 0, 0);
            }
        }
        __builtin_amdgcn_s_setprio(0);

        // K reads retired -> reuse Kl for next block
        asm volatile("s_waitcnt lgkmcnt(0)" ::: "memory");
        if (kb + 1 < KS) ISSUE8(Kh + bhbase + (size_t)jidx[kb + 1] * 4096, Kl);

        // ---- softmax: P = exp2(S); per-lane partial row sums; pack B-frags ----
        f16x4 e4[4][4];
        #pragma unroll
        for (int f = 0; f < 4; ++f) {
            #pragma unroll
            for (int t = 0; t < 4; ++t) {
                float x0 = __builtin_amdgcn_exp2f(sacc[f][t][0]);
                float x1 = __builtin_amdgcn_exp2f(sacc[f][t][1]);
                float x2 = __builtin_amdgcn_exp2f(sacc[f][t][2]);
                float x3 = __builtin_amdgcn_exp2f(sacc[f][t][3]);
                rl[f] += (x0 + x1) + (x2 + x3);
                e4[f][t] = pk4(x0, x1, x2, x3);
            }
        }

        // wait: V[kb] staged (K[kb+1] still in flight)
        if (kb + 1 < KS) asm volatile("s_waitcnt vmcnt(8)" ::: "memory");
        else             asm volatile("s_waitcnt vmcnt(0)" ::: "memory");

        // ---- PV: O^T += V^T P^T ; V fragments are single conflict-free b64 reads ----
        __builtin_amdgcn_s_setprio(1);
        #pragma unroll
        for (int tt = 0; tt < 4; ++tt) {
            #pragma unroll
            for (int t = 0; t < 4; ++t) {
                f16x4 va = *(const f16x4*)&Vl[(tt * 16 + c) * 64 + (((4 * t + g) ^ c) << 2)];
                #pragma unroll
                for (int f = 0; f < 4; ++f)
                    oacc[f][tt] = __builtin_amdgcn_mfma_f32_16x16x16f16(va, e4[f][t], oacc[f][tt], 0, 0, 0);
            }
        }
        __builtin_amdgcn_s_setprio(0);

        asm volatile("s_waitcnt lgkmcnt(0)" ::: "memory");
        if (kb + 1 < KS) ISSUE8(Vt + bhbase + (size_t)jidx[kb + 1] * 4096, Vl);
    }

    // ---- finalize row sums and store O ----
    #pragma unroll
    for (int f = 0; f < 4; ++f) {
        rl[f] += __shfl_xor(rl[f], 16);
        rl[f] += __shfl_xor(rl[f], 32);
    }
    #pragma unroll
    for (int f = 0; f < 4; ++f) {
        float inv = 1.0f / rl[f];
        float* orow = O + ((size_t)b * Sn + (size_t)nb * 64 + f * 16 + c) * HD + h * Dn;
        #pragma unroll
        for (int tt = 0; tt < 4; ++tt) {
            float4 o4;
            o4.x = oacc[f][tt][0] * inv; o4.y = oacc[f][tt][1] * inv;
            o4.z = oacc[f][tt][2] * inv; o4.w = oacc[f][tt][3] * inv;
            *(float4*)(orow + tt * 16 + g * 4) = o4;
        }
    }
}

// ======== kernel 3 (fallback): r7 f32-gather version, used only if ws is small ========
__global__ __launch_bounds__(64) void sla_attn32(const float* __restrict__ Q,
                                                 const float* __restrict__ K,
                                                 const float* __restrict__ V,
                                                 const int* __restrict__ topk,
                                                 float* __restrict__ O) {
    __shared__ float Kl[4096];
    __shared__ float Vl[4096];

    int raw = blockIdx.x;
    int bid = (raw & 7) * 256 + (raw >> 3);

    int b   = bid / (Hh * NB);
    int rem = bid % (Hh * NB);
    int h   = rem / NB;
    int nb  = rem % NB;

    int lane = threadIdx.x & 63;
    int c    = lane & 15;
    int g    = lane >> 4;

    const int* tkp = topk + (size_t)bid * KS;
    int j0 = __builtin_amdgcn_readfirstlane(tkp[0]);

    const float* kbase = K + (size_t)b * Sn * HD + h * Dn;
    const float* vbase = V + (size_t)b * Sn * HD + h * Dn;
    const float* qbase = Q + ((size_t)b * Sn + (size_t)nb * 64) * HD + h * Dn;

    int cx[4];
    #pragma unroll
    for (int j = 0; j < 4; ++j) cx[j] = (c ^ j) << 2;

    #define ISSUE16F(basep, blk, ldsarr) do {                                        \
        const float* _bp = (basep) + ((size_t)(blk) * 64 + g) * HD;                  \
        _Pragma("unroll")                                                            \
        for (int _ch = 0; _ch < 16; ++_ch) {                                         \
            const float* _src = _bp + (size_t)_ch * 4 * HD + cx[_ch & 3];            \
            __builtin_amdgcn_global_load_lds(                                        \
                (const __attribute__((address_space(1))) void*)_src,                 \
                (__attribute__((address_space(3))) void*)&(ldsarr)[_ch * 256],       \
                16, 0, 0);                                                           \
        }                                                                            \
    } while (0)

    float4 qraw[4][2][2];
    #pragma unroll
    for (int f = 0; f < 4; ++f) {
        const float* qrow = qbase + (size_t)(f * 16 + c) * HD;
        #pragma unroll
        for (int s2 = 0; s2 < 2; ++s2) {
            qraw[f][s2][0] = *(const float4*)(qrow + s2 * 32 + g * 8);
            qraw[f][s2][1] = *(const float4*)(qrow + s2 * 32 + g * 8 + 4);
        }
    }
    ISSUE16F(kbase, j0, Kl);
    ISSUE16F(vbase, j0, Vl);

    const float QS = 0.18033688f;
    f16x8 qf[4][2];
    #pragma unroll
    for (int f = 0; f < 4; ++f) {
        #pragma unroll
        for (int s2 = 0; s2 < 2; ++s2) {
            float4 a0 = qraw[f][s2][0], a1 = qraw[f][s2][1];
            f16x8 q;
            q[0] = (_Float16)(a0.x * QS); q[1] = (_Float16)(a0.y * QS);
            q[2] = (_Float16)(a0.z * QS); q[3] = (_Float16)(a0.w * QS);
            q[4] = (_Float16)(a1.x * QS); q[5] = (_Float16)(a1.y * QS);
            q[6] = (_Float16)(a1.z * QS); q[7] = (_Float16)(a1.w * QS);
            qf[f][s2] = q;
        }
    }

    f32x4 oacc[4][4];
    #pragma unroll
    for (int f = 0; f < 4; ++f)
        #pragma unroll
        for (int tt = 0; tt < 4; ++tt) oacc[f][tt] = f32x4{0.f, 0.f, 0.f, 0.f};
    float rl[4] = {0.f, 0.f, 0.f, 0.f};

    int o1 = (g << 3) ^ ((c >> 2) << 2);
    int vc = (g << 8) + (c ^ (g << 2));

    for (int kb = 0; kb < KS; ++kb) {
        int kn = (kb + 1 < KS) ? kb + 1 : 0;
        int jn = __builtin_amdgcn_readfirstlane(tkp[kn]);

        asm volatile("s_waitcnt vmcnt(16)" ::: "memory");

        f32x4 sacc[4][4];
        #pragma unroll
        for (int f = 0; f < 4; ++f)
            #pragma unroll
            for (int t = 0; t < 4; ++t) sacc[f][t] = f32x4{0.f, 0.f, 0.f, 0.f};
        #pragma unroll
        for (int t = 0; t < 4; ++t) {
            int rb = (t * 16 + c) * 64;
            float4 ka0 = *(const float4*)&Kl[rb + o1];
            float4 ka1 = *(const float4*)&Kl[rb + (o1 ^ 4)];
            float4 kb0 = *(const float4*)&Kl[rb + 32 + o1];
            float4 kb1 = *(const float4*)&Kl[rb + 32 + (o1 ^ 4)];
            f16x8 a0 = cvt8(ka0, ka1);
            f16x8 a1 = cvt8(kb0, kb1);
            #pragma unroll
            for (int f = 0; f < 4; ++f) {
                sacc[f][t] = __builtin_amdgcn_mfma_f32_16x16x32_f16(a0, qf[f][0], sacc[f][t], 0, 0, 0);
                sacc[f][t] = __builtin_amdgcn_mfma_f32_16x16x32_f16(a1, qf[f][1], sacc[f][t], 0, 0, 0);
            }
        }
        asm volatile("s_waitcnt lgkmcnt(0)" ::: "memory");
        if (kb + 1 < KS) ISSUE16F(kbase, jn, Kl);

        f16x4 e4[4][4];
        #pragma unroll
        for (int f = 0; f < 4; ++f) {
            #pragma unroll
            for (int t = 0; t < 4; ++t) {
                float x0 = __builtin_amdgcn_exp2f(sacc[f][t][0]);
                float x1 = __builtin_amdgcn_exp2f(sacc[f][t][1]);
                float x2 = __builtin_amdgcn_exp2f(sacc[f][t][2]);
                float x3 = __builtin_amdgcn_exp2f(sacc[f][t][3]);
                rl[f] += (x0 + x1) + (x2 + x3);
                e4[f][t] = pk4(x0, x1, x2, x3);
            }
        }

        if (kb + 1 < KS) asm volatile("s_waitcnt vmcnt(16)" ::: "memory");
        else             asm volatile("s_waitcnt vmcnt(0)"  ::: "memory");

        #pragma unroll
        for (int tt = 0; tt < 4; ++tt) {
            #pragma unroll
            for (int t = 0; t < 4; ++t) {
                int base = t * 1024 + tt * 16 + vc;
                float v0 = Vl[base];
                float v1 = Vl[base + 64];
                float v2 = Vl[base + 128];
                float v3 = Vl[base + 192];
                f16x4 va = pk4(v0, v1, v2, v3);
                #pragma unroll
                for (int f = 0; f < 4; ++f)
                    oacc[f][tt] = __builtin_amdgcn_mfma_f32_16x16x16f16(va, e4[f][t], oacc[f][tt], 0, 0, 0);
            }
        }
        asm volatile("s_waitcnt lgkmcnt(0)" ::: "memory");
        if (kb + 1 < KS) ISSUE16F(vbase, jn, Vl);
    }

    #pragma unroll
    for (int f = 0; f < 4; ++f) {
        rl[f] += __shfl_xor(rl[f], 16);
        rl[f] += __shfl_xor(rl[f], 32);
    }
    #pragma unroll
    for (int f = 0; f < 4; ++f) {
        float inv = 1.0f / rl[f];
        float* orow = O + ((size_t)b * Sn + (size_t)nb * 64 + f * 16 + c) * HD + h * Dn;
        #pragma unroll
        for (int tt = 0; tt < 4; ++tt) {
            float4 o4;
            o4.x = oacc[f][tt][0] * inv; o4.y = oacc[f][tt][1] * inv;
            o4.z = oacc[f][tt][2] * inv; o4.w = oacc[f][tt][3] * inv;
            *(float4*)(orow + tt * 16 + g * 4) = o4;
        }
    }
    #undef ISSUE16F
}

extern "C" void kernel_launch(void* const* d_in, const int* in_sizes, int n_in,
                              void* d_out, int out_size, void* d_ws, size_t ws_size,
                              hipStream_t stream) {
    const float* Q = (const float*)d_in[0];
    const float* K = (const float*)d_in[1];
    const float* V = (const float*)d_in[2];
    float* O = (float*)d_out;

    constexpr size_t NPOOL = (size_t)Bn * Hh * NB * Dn;       // 131072
    constexpr size_t NTOPK = (size_t)Bn * Hh * NB * KS;       // 14336
    constexpr size_t NBLK  = (size_t)Bn * Hh * NB * 64 * 64;  // 8388608 f16 elems

    float* qpool = (float*)d_ws;
    float* kpool = qpool + NPOOL;
    int*   topk  = (int*)(kpool + NPOOL);
    _Float16* Kh = (_Float16*)(topk + NTOPK);
    _Float16* Vt = Kh + NBLK;

    size_t need = 2 * NPOOL * 4 + NTOPK * 4 + 2 * NBLK * 2;   // ~34.7 MB

    dim3 grid(Bn * Hh * NB);
    if (ws_size >= need) {
        sla_prep<<<grid, 256, 0, stream>>>(Q, K, V, qpool, kpool, Kh, Vt);
        sla_topk<<<grid, 64, 0, stream>>>(qpool, kpool, topk);
        sla_attn16<<<grid, 64, 0, stream>>>(Q, Kh, Vt, topk, O);
    } else {
        sla_pool<<<grid, 64, 0, stream>>>(Q, K, qpool, kpool);
        sla_topk<<<grid, 64, 0, stream>>>(qpool, kpool, topk);
        sla_attn32<<<grid, 64, 0, stream>>>(Q, K, V, topk, O);
    }
}

// Round 10
// 84.930 us; speedup vs baseline: 1.9123x; 1.9123x over previous
//
#include <hip/hip_runtime.h>

constexpr int Bn = 2;
constexpr int Sn = 4096;
constexpr int Hh = 16;
constexpr int Dn = 64;
constexpr int HD = 1024;   // Hh * Dn
constexpr int NB = 64;     // Sn / 64
constexpr int KS = 7;      // ceil(0.1 * 64)

typedef _Float16 f16x8 __attribute__((ext_vector_type(8)));
typedef _Float16 f16x4 __attribute__((ext_vector_type(4)));
typedef _Float16 f16x2 __attribute__((ext_vector_type(2)));
typedef __fp16   hf2   __attribute__((ext_vector_type(2)));
typedef float    f32x4 __attribute__((ext_vector_type(4)));

static __device__ __forceinline__ f16x8 cvt8(float4 a, float4 b) {
    f16x8 r;
    r[0] = (_Float16)a.x; r[1] = (_Float16)a.y;
    r[2] = (_Float16)a.z; r[3] = (_Float16)a.w;
    r[4] = (_Float16)b.x; r[5] = (_Float16)b.y;
    r[6] = (_Float16)b.z; r[7] = (_Float16)b.w;
    return r;
}

static __device__ __forceinline__ f16x4 pk4(float a, float b, float c, float d) {
    hf2 lo = __builtin_amdgcn_cvt_pkrtz(a, b);
    hf2 hi = __builtin_amdgcn_cvt_pkrtz(c, d);
    f16x2 l2 = __builtin_bit_cast(f16x2, lo);
    f16x2 h2 = __builtin_bit_cast(f16x2, hi);
    f16x4 r;
    r[0] = l2[0]; r[1] = l2[1]; r[2] = h2[0]; r[3] = h2[1];
    return r;
}

// ============ kernel 0 (fast path): fused pool + f16 convert/transpose ============
// Kh[bid][key][d]: f16, 16B chunk ch of row stored at slot ch^(key&7)  (LDS-bank
// swizzle baked into GLOBAL layout so attn's global_load_lds copy is linear).
// Vt[bid][d][key]: f16 transposed; 4-elem chunk (key>>2) stored at slot (key>>2)^(d&15).
__global__ __launch_bounds__(256) void sla_prep(const float* __restrict__ Q,
                                                const float* __restrict__ K,
                                                const float* __restrict__ V,
                                                float* __restrict__ qpool,
                                                float* __restrict__ kpool,
                                                _Float16* __restrict__ Kh,
                                                _Float16* __restrict__ Vt) {
    __shared__ float Tl[64][68];          // stride 68: 16B-aligned rows, bank-rotated

    int bid = blockIdx.x;                 // (b*Hh + h)*NB + nb
    int b   = bid / (Hh * NB);
    int rem = bid % (Hh * NB);
    int h   = rem / NB;
    int nb  = rem % NB;

    int t  = threadIdx.x;
    int r  = t >> 2;                      // row / key 0..63
    int q4 = t & 3;
    int dq = q4 << 4;

    const size_t rowbase = ((size_t)b * Sn + (size_t)nb * 64) * HD + h * Dn;
    const float* qp = Q + rowbase + (size_t)r * HD + dq;
    const float* kp = K + rowbase + (size_t)r * HD + dq;
    const float* vp = V + rowbase + (size_t)r * HD + dq;

    float4 qx[4], kx[4], vx[4];
    #pragma unroll
    for (int i = 0; i < 4; ++i) qx[i] = *(const float4*)(qp + i * 4);
    #pragma unroll
    for (int i = 0; i < 4; ++i) kx[i] = *(const float4*)(kp + i * 4);
    #pragma unroll
    for (int i = 0; i < 4; ++i) vx[i] = *(const float4*)(vp + i * 4);

    // ---- Q: stage + fp64 column means ----
    #pragma unroll
    for (int i = 0; i < 4; ++i) *(float4*)&Tl[r][dq + i * 4] = qx[i];
    __syncthreads();
    if (t < 64) {
        double s = 0.0;
        #pragma unroll 8
        for (int rr = 0; rr < 64; ++rr) s += (double)Tl[rr][t];
        qpool[(size_t)bid * 64 + t] = (float)(s * (1.0 / 64.0));
    }
    __syncthreads();

    // ---- K: write swizzled f16 + stage + fp64 column means ----
    {
        _Float16* khrow = Kh + ((size_t)bid * 64 + r) * 64;
        int s0 = ((q4 << 1) + 0) ^ (r & 7);
        int s1 = ((q4 << 1) + 1) ^ (r & 7);
        *(f16x8*)(khrow + (s0 << 3)) = cvt8(kx[0], kx[1]);   // d dq..dq+7
        *(f16x8*)(khrow + (s1 << 3)) = cvt8(kx[2], kx[3]);   // d dq+8..dq+15
    }
    #pragma unroll
    for (int i = 0; i < 4; ++i) *(float4*)&Tl[r][dq + i * 4] = kx[i];
    __syncthreads();
    if (t < 64) {
        double s = 0.0;
        #pragma unroll 8
        for (int rr = 0; rr < 64; ++rr) s += (double)Tl[rr][t];
        kpool[(size_t)bid * 64 + t] = (float)(s * (1.0 / 64.0));
    }
    __syncthreads();

    // ---- V: stage, then write transposed + swizzled f16 ----
    #pragma unroll
    for (int i = 0; i < 4; ++i) *(float4*)&Tl[r][dq + i * 4] = vx[i];
    __syncthreads();
    {
        int d  = r;                       // output row = d
        _Float16* vtrow = Vt + ((size_t)bid * 64 + d) * 64;
        #pragma unroll
        for (int si = 0; si < 4; ++si) {
            int s  = (q4 << 2) + si;      // slot 0..15
            int ch = s ^ (d & 15);        // key chunk stored at this slot
            f16x4 v4;
            v4[0] = (_Float16)Tl[(ch << 2) + 0][d];
            v4[1] = (_Float16)Tl[(ch << 2) + 1][d];
            v4[2] = (_Float16)Tl[(ch << 2) + 2][d];
            v4[3] = (_Float16)Tl[(ch << 2) + 3][d];
            *(f16x4*)(vtrow + (s << 2)) = v4;
        }
    }
}

// ---------------- kernel 1 (fallback path): per-block mean pooling ----------------
__global__ __launch_bounds__(64) void sla_pool(const float* __restrict__ Q,
                                               const float* __restrict__ K,
                                               float* __restrict__ qpool,
                                               float* __restrict__ kpool) {
    int bid  = blockIdx.x;
    int b    = bid / (Hh * NB);
    int rem  = bid % (Hh * NB);
    int h    = rem / NB;
    int nb   = rem % NB;
    int tid  = threadIdx.x;
    int quad = tid >> 4;
    int dq   = (tid & 15) << 2;

    const float* qb = Q + ((size_t)b * Sn + (size_t)nb * 64) * HD + h * Dn + dq;
    const float* kb = K + ((size_t)b * Sn + (size_t)nb * 64) * HD + h * Dn + dq;

    double sq[4] = {0, 0, 0, 0}, sk[4] = {0, 0, 0, 0};
    #pragma unroll
    for (int i = 0; i < 16; ++i) {
        size_t off = (size_t)(quad + i * 4) * HD;
        float4 x = *(const float4*)(qb + off);
        float4 y = *(const float4*)(kb + off);
        sq[0] += x.x; sq[1] += x.y; sq[2] += x.z; sq[3] += x.w;
        sk[0] += y.x; sk[1] += y.y; sk[2] += y.z; sk[3] += y.w;
    }
    #pragma unroll
    for (int j = 0; j < 4; ++j) {
        sq[j] += __shfl_xor(sq[j], 16); sq[j] += __shfl_xor(sq[j], 32);
        sk[j] += __shfl_xor(sk[j], 16); sk[j] += __shfl_xor(sk[j], 32);
    }
    if (quad == 0) {
        float4 oq, ok;
        oq.x = (float)(sq[0] * (1.0 / 64.0)); oq.y = (float)(sq[1] * (1.0 / 64.0));
        oq.z = (float)(sq[2] * (1.0 / 64.0)); oq.w = (float)(sq[3] * (1.0 / 64.0));
        ok.x = (float)(sk[0] * (1.0 / 64.0)); ok.y = (float)(sk[1] * (1.0 / 64.0));
        ok.z = (float)(sk[2] * (1.0 / 64.0)); ok.w = (float)(sk[3] * (1.0 / 64.0));
        *(float4*)(qpool + (size_t)bid * 64 + dq) = oq;
        *(float4*)(kpool + (size_t)bid * 64 + dq) = ok;
    }
}

// -------- kernel 2: block scores (fp64) + top-7 selection (lax.top_k ties: lower idx) --------
__global__ __launch_bounds__(64) void sla_topk(const float* __restrict__ qpool,
                                               const float* __restrict__ kpool,
                                               int* __restrict__ topk) {
    int bid = blockIdx.x;
    int bh  = bid / NB;
    int j   = threadIdx.x;

    const float* qp = qpool + (size_t)bid * 64;
    const float* kp = kpool + ((size_t)bh * NB + j) * 64;
    double s = 0.0;
    #pragma unroll 8
    for (int d = 0; d < 64; ++d) s += (double)qp[d] * (double)kp[d];

    double v  = s;
    int   idx = j;
    #pragma unroll
    for (int it = 0; it < KS; ++it) {
        double bv = v; int bi = idx;
        #pragma unroll
        for (int off = 1; off < 64; off <<= 1) {
            double ov = __shfl_xor(bv, off);
            int    oi = __shfl_xor(bi, off);
            if (ov > bv || (ov == bv && oi < bi)) { bv = ov; bi = oi; }
        }
        if (j == 0) topk[(size_t)bid * KS + it] = bi;
        if (idx == bi) v = -1e300;
    }
}

// ======== kernel 3 (fast path): 1-wave flash attention over pre-converted f16 ========
// Rolled kb loop (no spill); next-block index via uniform cselect chain; per-t sacc
// (16 VGPR slice dies into e4). Linear 8KB global_load_lds; counted vmcnt(8) pipeline.
__global__ __launch_bounds__(64) void sla_attn16(const float* __restrict__ Q,
                                                 const _Float16* __restrict__ Kh,
                                                 const _Float16* __restrict__ Vt,
                                                 const int* __restrict__ topk,
                                                 float* __restrict__ O) {
    __shared__ _Float16 Kl[4096];         // 8KB [key][slot] (pre-swizzled)
    __shared__ _Float16 Vl[4096];         // 8KB [d][slot]   (pre-swizzled)

    int raw = blockIdx.x;
    int bid = (raw & 7) * 256 + (raw >> 3);   // XCD-chunked swizzle (2048 = 8*256)

    int b   = bid / (Hh * NB);
    int rem = bid % (Hh * NB);
    int h   = rem / NB;
    int nb  = rem % NB;

    int lane = threadIdx.x & 63;
    int c    = lane & 15;
    int g    = lane >> 4;

    // hoist 7 block indices to SGPRs (constant indices -> scalar loads, no scratch)
    const int* tkp = topk + (size_t)bid * KS;
    int j0 = __builtin_amdgcn_readfirstlane(tkp[0]);
    int j1 = __builtin_amdgcn_readfirstlane(tkp[1]);
    int j2 = __builtin_amdgcn_readfirstlane(tkp[2]);
    int j3 = __builtin_amdgcn_readfirstlane(tkp[3]);
    int j4 = __builtin_amdgcn_readfirstlane(tkp[4]);
    int j5 = __builtin_amdgcn_readfirstlane(tkp[5]);
    int j6 = __builtin_amdgcn_readfirstlane(tkp[6]);

    const size_t bhbase = (size_t)(bid - nb) * 4096;   // (bh*NB)*4096
    const float* qbase  = Q + ((size_t)b * Sn + (size_t)nb * 64) * HD + h * Dn;

    // linear 8KB copy: 8 chunks x (64 lanes x 16B = 1024B = 512 f16)
    auto ISSUE8 = [&](const _Float16* blkbase, _Float16* ldsbase) {
        #pragma unroll
        for (int ch = 0; ch < 8; ++ch) {
            const _Float16* src = blkbase + ch * 512 + lane * 8;
            __builtin_amdgcn_global_load_lds(
                (const __attribute__((address_space(1))) void*)src,
                (__attribute__((address_space(3))) void*)(ldsbase + ch * 512),
                16, 0, 0);
        }
    };

    // ---- Q loads first (oldest vmcnt slots), then block-0 staging ----
    float4 qraw[4][2][2];
    #pragma unroll
    for (int f = 0; f < 4; ++f) {
        const float* qrow = qbase + (size_t)(f * 16 + c) * HD;
        #pragma unroll
        for (int s2 = 0; s2 < 2; ++s2) {
            qraw[f][s2][0] = *(const float4*)(qrow + s2 * 32 + g * 8);
            qraw[f][s2][1] = *(const float4*)(qrow + s2 * 32 + g * 8 + 4);
        }
    }
    ISSUE8(Kh + bhbase + (size_t)j0 * 4096, Kl);
    ISSUE8(Vt + bhbase + (size_t)j0 * 4096, Vl);

    // ---- Q fragments; scale = 0.125 * log2(e) (softmax in log2 domain) ----
    const float QS = 0.18033688f;
    f16x8 qf[4][2];
    #pragma unroll
    for (int f = 0; f < 4; ++f) {
        #pragma unroll
        for (int s2 = 0; s2 < 2; ++s2) {
            float4 a0 = qraw[f][s2][0], a1 = qraw[f][s2][1];
            f16x8 q;
            q[0] = (_Float16)(a0.x * QS); q[1] = (_Float16)(a0.y * QS);
            q[2] = (_Float16)(a0.z * QS); q[3] = (_Float16)(a0.w * QS);
            q[4] = (_Float16)(a1.x * QS); q[5] = (_Float16)(a1.y * QS);
            q[6] = (_Float16)(a1.z * QS); q[7] = (_Float16)(a1.w * QS);
            qf[f][s2] = q;
        }
    }

    f32x4 oacc[4][4];
    #pragma unroll
    for (int f = 0; f < 4; ++f)
        #pragma unroll
        for (int tt = 0; tt < 4; ++tt) oacc[f][tt] = f32x4{0.f, 0.f, 0.f, 0.f};
    float rl[4] = {0.f, 0.f, 0.f, 0.f};

    int ks0 = (g ^ (c & 7)) << 3;         // QK slot offset (f16) within 64-elem row

    for (int kb = 0; kb < KS; ++kb) {     // ROLLED: keeps one iteration's state live
        // next-block index: kb is wave-uniform -> s_cselect chain, no scratch
        int jn = j1;
        jn = (kb == 1) ? j2 : jn;
        jn = (kb == 2) ? j3 : jn;
        jn = (kb == 3) ? j4 : jn;
        jn = (kb == 4) ? j5 : jn;
        jn = (kb == 5) ? j6 : jn;

        // wait: K[kb] staged (V[kb] batch of 8 still in flight)
        asm volatile("s_waitcnt vmcnt(8)" ::: "memory");

        // ---- QK + softmax fused per key-tile t: sacc slice (16 VGPR) dies into e4 ----
        f16x4 e4[4][4];                   // [f][t], 16 VGPRs
        __builtin_amdgcn_s_setprio(1);
        #pragma unroll
        for (int t = 0; t < 4; ++t) {
            int rb = (t * 16 + c) * 64;
            f16x8 a0 = *(const f16x8*)&Kl[rb + ks0];          // d 8g..8g+7
            f16x8 a1 = *(const f16x8*)&Kl[rb + (ks0 ^ 32)];   // d 32+8g..+7
            f32x4 s0 = __builtin_amdgcn_mfma_f32_16x16x32_f16(a0, qf[0][0], f32x4{0.f,0.f,0.f,0.f}, 0, 0, 0);
            f32x4 s1 = __builtin_amdgcn_mfma_f32_16x16x32_f16(a0, qf[1][0], f32x4{0.f,0.f,0.f,0.f}, 0, 0, 0);
            f32x4 s2 = __builtin_amdgcn_mfma_f32_16x16x32_f16(a0, qf[2][0], f32x4{0.f,0.f,0.f,0.f}, 0, 0, 0);
            f32x4 s3 = __builtin_amdgcn_mfma_f32_16x16x32_f16(a0, qf[3][0], f32x4{0.f,0.f,0.f,0.f}, 0, 0, 0);
            s0 = __builtin_amdgcn_mfma_f32_16x16x32_f16(a1, qf[0][1], s0, 0, 0, 0);
            s1 = __builtin_amdgcn_mfma_f32_16x16x32_f16(a1, qf[1][1], s1, 0, 0, 0);
            s2 = __builtin_amdgcn_mfma_f32_16x16x32_f16(a1, qf[2][1], s2, 0, 0, 0);
            s3 = __builtin_amdgcn_mfma_f32_16x16x32_f16(a1, qf[3][1], s3, 0, 0, 0);
            float x0, x1, x2, x3;
            x0 = __builtin_amdgcn_exp2f(s0[0]); x1 = __builtin_amdgcn_exp2f(s0[1]);
            x2 = __builtin_amdgcn_exp2f(s0[2]); x3 = __builtin_amdgcn_exp2f(s0[3]);
            rl[0] += (x0 + x1) + (x2 + x3); e4[0][t] = pk4(x0, x1, x2, x3);
            x0 = __builtin_amdgcn_exp2f(s1[0]); x1 = __builtin_amdgcn_exp2f(s1[1]);
            x2 = __builtin_amdgcn_exp2f(s1[2]); x3 = __builtin_amdgcn_exp2f(s1[3]);
            rl[1] += (x0 + x1) + (x2 + x3); e4[1][t] = pk4(x0, x1, x2, x3);
            x0 = __builtin_amdgcn_exp2f(s2[0]); x1 = __builtin_amdgcn_exp2f(s2[1]);
            x2 = __builtin_amdgcn_exp2f(s2[2]); x3 = __builtin_amdgcn_exp2f(s2[3]);
            rl[2] += (x0 + x1) + (x2 + x3); e4[2][t] = pk4(x0, x1, x2, x3);
            x0 = __builtin_amdgcn_exp2f(s3[0]); x1 = __builtin_amdgcn_exp2f(s3[1]);
            x2 = __builtin_amdgcn_exp2f(s3[2]); x3 = __builtin_amdgcn_exp2f(s3[3]);
            rl[3] += (x0 + x1) + (x2 + x3); e4[3][t] = pk4(x0, x1, x2, x3);
        }
        __builtin_amdgcn_s_setprio(0);

        // K reads retired -> reuse Kl for next block
        asm volatile("s_waitcnt lgkmcnt(0)" ::: "memory");
        if (kb + 1 < KS) ISSUE8(Kh + bhbase + (size_t)jn * 4096, Kl);

        // wait: V[kb] staged (K[kb+1] batch of 8 still in flight)
        if (kb + 1 < KS) asm volatile("s_waitcnt vmcnt(8)" ::: "memory");
        else             asm volatile("s_waitcnt vmcnt(0)" ::: "memory");

        // ---- PV: O^T += V^T P^T ; V fragments are single conflict-free b64 reads ----
        __builtin_amdgcn_s_setprio(1);
        #pragma unroll
        for (int tt = 0; tt < 4; ++tt) {
            #pragma unroll
            for (int t = 0; t < 4; ++t) {
                f16x4 va = *(const f16x4*)&Vl[(tt * 16 + c) * 64 + (((4 * t + g) ^ c) << 2)];
                #pragma unroll
                for (int f = 0; f < 4; ++f)
                    oacc[f][tt] = __builtin_amdgcn_mfma_f32_16x16x16f16(va, e4[f][t], oacc[f][tt], 0, 0, 0);
            }
        }
        __builtin_amdgcn_s_setprio(0);

        asm volatile("s_waitcnt lgkmcnt(0)" ::: "memory");
        if (kb + 1 < KS) ISSUE8(Vt + bhbase + (size_t)jn * 4096, Vl);
    }

    // ---- finalize row sums and store O ----
    #pragma unroll
    for (int f = 0; f < 4; ++f) {
        rl[f] += __shfl_xor(rl[f], 16);
        rl[f] += __shfl_xor(rl[f], 32);
    }
    #pragma unroll
    for (int f = 0; f < 4; ++f) {
        float inv = 1.0f / rl[f];
        float* orow = O + ((size_t)b * Sn + (size_t)nb * 64 + f * 16 + c) * HD + h * Dn;
        #pragma unroll
        for (int tt = 0; tt < 4; ++tt) {
            float4 o4;
            o4.x = oacc[f][tt][0] * inv; o4.y = oacc[f][tt][1] * inv;
            o4.z = oacc[f][tt][2] * inv; o4.w = oacc[f][tt][3] * inv;
            *(float4*)(orow + tt * 16 + g * 4) = o4;
        }
    }
}

// ======== kernel 3 (fallback): r7 f32-gather version, used only if ws is small ========
__global__ __launch_bounds__(64) void sla_attn32(const float* __restrict__ Q,
                                                 const float* __restrict__ K,
                                                 const float* __restrict__ V,
                                                 const int* __restrict__ topk,
                                                 float* __restrict__ O) {
    __shared__ float Kl[4096];
    __shared__ float Vl[4096];

    int raw = blockIdx.x;
    int bid = (raw & 7) * 256 + (raw >> 3);

    int b   = bid / (Hh * NB);
    int rem = bid % (Hh * NB);
    int h   = rem / NB;
    int nb  = rem % NB;

    int lane = threadIdx.x & 63;
    int c    = lane & 15;
    int g    = lane >> 4;

    const int* tkp = topk + (size_t)bid * KS;
    int j0 = __builtin_amdgcn_readfirstlane(tkp[0]);

    const float* kbase = K + (size_t)b * Sn * HD + h * Dn;
    const float* vbase = V + (size_t)b * Sn * HD + h * Dn;
    const float* qbase = Q + ((size_t)b * Sn + (size_t)nb * 64) * HD + h * Dn;

    int cx[4];
    #pragma unroll
    for (int j = 0; j < 4; ++j) cx[j] = (c ^ j) << 2;

    #define ISSUE16F(basep, blk, ldsarr) do {                                        \
        const float* _bp = (basep) + ((size_t)(blk) * 64 + g) * HD;                  \
        _Pragma("unroll")                                                            \
        for (int _ch = 0; _ch < 16; ++_ch) {                                         \
            const float* _src = _bp + (size_t)_ch * 4 * HD + cx[_ch & 3];            \
            __builtin_amdgcn_global_load_lds(                                        \
                (const __attribute__((address_space(1))) void*)_src,                 \
                (__attribute__((address_space(3))) void*)&(ldsarr)[_ch * 256],       \
                16, 0, 0);                                                           \
        }                                                                            \
    } while (0)

    float4 qraw[4][2][2];
    #pragma unroll
    for (int f = 0; f < 4; ++f) {
        const float* qrow = qbase + (size_t)(f * 16 + c) * HD;
        #pragma unroll
        for (int s2 = 0; s2 < 2; ++s2) {
            qraw[f][s2][0] = *(const float4*)(qrow + s2 * 32 + g * 8);
            qraw[f][s2][1] = *(const float4*)(qrow + s2 * 32 + g * 8 + 4);
        }
    }
    ISSUE16F(kbase, j0, Kl);
    ISSUE16F(vbase, j0, Vl);

    const float QS = 0.18033688f;
    f16x8 qf[4][2];
    #pragma unroll
    for (int f = 0; f < 4; ++f) {
        #pragma unroll
        for (int s2 = 0; s2 < 2; ++s2) {
            float4 a0 = qraw[f][s2][0], a1 = qraw[f][s2][1];
            f16x8 q;
            q[0] = (_Float16)(a0.x * QS); q[1] = (_Float16)(a0.y * QS);
            q[2] = (_Float16)(a0.z * QS); q[3] = (_Float16)(a0.w * QS);
            q[4] = (_Float16)(a1.x * QS); q[5] = (_Float16)(a1.y * QS);
            q[6] = (_Float16)(a1.z * QS); q[7] = (_Float16)(a1.w * QS);
            qf[f][s2] = q;
        }
    }

    f32x4 oacc[4][4];
    #pragma unroll
    for (int f = 0; f < 4; ++f)
        #pragma unroll
        for (int tt = 0; tt < 4; ++tt) oacc[f][tt] = f32x4{0.f, 0.f, 0.f, 0.f};
    float rl[4] = {0.f, 0.f, 0.f, 0.f};

    int o1 = (g << 3) ^ ((c >> 2) << 2);
    int vc = (g << 8) + (c ^ (g << 2));

    for (int kb = 0; kb < KS; ++kb) {
        int kn = (kb + 1 < KS) ? kb + 1 : 0;
        int jn = __builtin_amdgcn_readfirstlane(tkp[kn]);

        asm volatile("s_waitcnt vmcnt(16)" ::: "memory");

        f32x4 sacc[4][4];
        #pragma unroll
        for (int f = 0; f < 4; ++f)
            #pragma unroll
            for (int t = 0; t < 4; ++t) sacc[f][t] = f32x4{0.f, 0.f, 0.f, 0.f};
        #pragma unroll
        for (int t = 0; t < 4; ++t) {
            int rb = (t * 16 + c) * 64;
            float4 ka0 = *(const float4*)&Kl[rb + o1];
            float4 ka1 = *(const float4*)&Kl[rb + (o1 ^ 4)];
            float4 kb0 = *(const float4*)&Kl[rb + 32 + o1];
            float4 kb1 = *(const float4*)&Kl[rb + 32 + (o1 ^ 4)];
            f16x8 a0 = cvt8(ka0, ka1);
            f16x8 a1 = cvt8(kb0, kb1);
            #pragma unroll
            for (int f = 0; f < 4; ++f) {
                sacc[f][t] = __builtin_amdgcn_mfma_f32_16x16x32_f16(a0, qf[f][0], sacc[f][t], 0, 0, 0);
                sacc[f][t] = __builtin_amdgcn_mfma_f32_16x16x32_f16(a1, qf[f][1], sacc[f][t], 0, 0, 0);
            }
        }
        asm volatile("s_waitcnt lgkmcnt(0)" ::: "memory");
        if (kb + 1 < KS) ISSUE16F(kbase, jn, Kl);

        f16x4 e4[4][4];
        #pragma unroll
        for (int f = 0; f < 4; ++f) {
            #pragma unroll
            for (int t = 0; t < 4; ++t) {
                float x0 = __builtin_amdgcn_exp2f(sacc[f][t][0]);
                float x1 = __builtin_amdgcn_exp2f(sacc[f][t][1]);
                float x2 = __builtin_amdgcn_exp2f(sacc[f][t][2]);
                float x3 = __builtin_amdgcn_exp2f(sacc[f][t][3]);
                rl[f] += (x0 + x1) + (x2 + x3);
                e4[f][t] = pk4(x0, x1, x2, x3);
            }
        }

        if (kb + 1 < KS) asm volatile("s_waitcnt vmcnt(16)" ::: "memory");
        else             asm volatile("s_waitcnt vmcnt(0)"  ::: "memory");

        #pragma unroll
        for (int tt = 0; tt < 4; ++tt) {
            #pragma unroll
            for (int t = 0; t < 4; ++t) {
                int base = t * 1024 + tt * 16 + vc;
                float v0 = Vl[base];
                float v1 = Vl[base + 64];
                float v2 = Vl[base + 128];
                float v3 = Vl[base + 192];
                f16x4 va = pk4(v0, v1, v2, v3);
                #pragma unroll
                for (int f = 0; f < 4; ++f)
                    oacc[f][tt] = __builtin_amdgcn_mfma_f32_16x16x16f16(va, e4[f][t], oacc[f][tt], 0, 0, 0);
            }
        }
        asm volatile("s_waitcnt lgkmcnt(0)" ::: "memory");
        if (kb + 1 < KS) ISSUE16F(vbase, jn, Vl);
    }

    #pragma unroll
    for (int f = 0; f < 4; ++f) {
        rl[f] += __shfl_xor(rl[f], 16);
        rl[f] += __shfl_xor(rl[f], 32);
    }
    #pragma unroll
    for (int f = 0; f < 4; ++f) {
        float inv = 1.0f / rl[f];
        float* orow = O + ((size_t)b * Sn + (size_t)nb * 64 + f * 16 + c) * HD + h * Dn;
        #pragma unroll
        for (int tt = 0; tt < 4; ++tt) {
            float4 o4;
            o4.x = oacc[f][tt][0] * inv; o4.y = oacc[f][tt][1] * inv;
            o4.z = oacc[f][tt][2] * inv; o4.w = oacc[f][tt][3] * inv;
            *(float4*)(orow + tt * 16 + g * 4) = o4;
        }
    }
    #undef ISSUE16F
}

extern "C" void kernel_launch(void* const* d_in, const int* in_sizes, int n_in,
                              void* d_out, int out_size, void* d_ws, size_t ws_size,
                              hipStream_t stream) {
    const float* Q = (const float*)d_in[0];
    const float* K = (const float*)d_in[1];
    const float* V = (const float*)d_in[2];
    float* O = (float*)d_out;

    constexpr size_t NPOOL = (size_t)Bn * Hh * NB * Dn;       // 131072
    constexpr size_t NTOPK = (size_t)Bn * Hh * NB * KS;       // 14336
    constexpr size_t NBLK  = (size_t)Bn * Hh * NB * 64 * 64;  // 8388608 f16 elems

    float* qpool = (float*)d_ws;
    float* kpool = qpool + NPOOL;
    int*   topk  = (int*)(kpool + NPOOL);
    _Float16* Kh = (_Float16*)(topk + NTOPK);
    _Float16* Vt = Kh + NBLK;

    size_t need = 2 * NPOOL * 4 + NTOPK * 4 + 2 * NBLK * 2;   // ~34.7 MB

    dim3 grid(Bn * Hh * NB);
    if (ws_size >= need) {
        sla_prep<<<grid, 256, 0, stream>>>(Q, K, V, qpool, kpool, Kh, Vt);
        sla_topk<<<grid, 64, 0, stream>>>(qpool, kpool, topk);
        sla_attn16<<<grid, 64, 0, stream>>>(Q, Kh, Vt, topk, O);
    } else {
        sla_pool<<<grid, 64, 0, stream>>>(Q, K, qpool, kpool);
        sla_topk<<<grid, 64, 0, stream>>>(qpool, kpool, topk);
        sla_attn32<<<grid, 64, 0, stream>>>(Q, K, V, topk, O);
    }
}